// Round 6
// baseline (381.382 us; speedup 1.0000x reference)
//
#include <hip/hip_runtime.h>
#include <hip/hip_fp16.h>

// GCN 2-layer: out = A_hat @ relu(A_hat @ (X W1) + b1) W2 + b2
// A_hat = D^-1/2 (A+I) D^-1/2.
// R6: (1) fill/degree reverted to R5-regressed -> R4 form (1 edge/thread: the
//     scatter is atomic-latency bound; 4x ILP cut threads 1.6M->400k and lost,
//     118 vs 68 us at identical 62 MB WRITE).
//     (2) gather split into two 32-col passes: per-pass xwh working set 3.2 MB
//     fits the 4 MB per-XCD L2 (one 6.4 MB pass thrashes to LLC); agg/out
//     written nontemporal (full-line) so the output stream doesn't evict it.

// ---- degree, bucketed by x = blockIdx&7 (256 edges per block) ----
__global__ void degree8_kernel(const int* __restrict__ dst, unsigned* __restrict__ deg8,
                               int n, int e) {
    int t = blockIdx.x * blockDim.x + threadIdx.x;
    if (t >= e) return;
    int x = blockIdx.x & 7;
    atomicAdd(&deg8[x * n + dst[t]], 1u);
}

// ---- block scans ----
__global__ void scanA_local(const unsigned* __restrict__ deg8, unsigned* __restrict__ rp8,
                            unsigned* __restrict__ partials, int m) {
    __shared__ unsigned sh[1024];
    int i = blockIdx.x * 1024 + threadIdx.x;
    unsigned v = (i < m) ? deg8[i] : 0u;
    sh[threadIdx.x] = v;
    __syncthreads();
    for (int off = 1; off < 1024; off <<= 1) {
        unsigned t = (threadIdx.x >= (unsigned)off) ? sh[threadIdx.x - off] : 0u;
        __syncthreads();
        sh[threadIdx.x] += t;
        __syncthreads();
    }
    if (i < m) rp8[i] = sh[threadIdx.x] - v;  // exclusive
    if (threadIdx.x == 1023) partials[blockIdx.x] = sh[1023];
}

// node-total degrees -> rpf (pre-add); dinv fused
__global__ void scanB_local(const unsigned* __restrict__ deg8, unsigned* __restrict__ rpf,
                            unsigned* __restrict__ partials, float* __restrict__ dinv, int n) {
    __shared__ unsigned sh[1024];
    int i = blockIdx.x * 1024 + threadIdx.x;
    unsigned v = 0;
    if (i < n) {
#pragma unroll
        for (int x = 0; x < 8; ++x) v += deg8[x * n + i];
        dinv[i] = rsqrtf((float)v + 1.0f);  // +1 self-loop; always > 0
    }
    sh[threadIdx.x] = v;
    __syncthreads();
    for (int off = 1; off < 1024; off <<= 1) {
        unsigned t = (threadIdx.x >= (unsigned)off) ? sh[threadIdx.x - off] : 0u;
        __syncthreads();
        sh[threadIdx.x] += t;
        __syncthreads();
    }
    if (i < n) rpf[i] = sh[threadIdx.x] - v;  // exclusive
    if (threadIdx.x == 1023) partials[blockIdx.x] = sh[1023];
}

// block 0 scans partialsA[mA_], block 1 scans partialsB[mB_] (both <= 1024)
__global__ void scan_partials_both(unsigned* __restrict__ pA, int mA_,
                                   unsigned* __restrict__ pB, int mB_) {
    __shared__ unsigned sh[1024];
    unsigned* p = blockIdx.x ? pB : pA;
    int m = blockIdx.x ? mB_ : mA_;
    unsigned v = (threadIdx.x < (unsigned)m) ? p[threadIdx.x] : 0u;
    sh[threadIdx.x] = v;
    __syncthreads();
    for (int off = 1; off < 1024; off <<= 1) {
        unsigned t = (threadIdx.x >= (unsigned)off) ? sh[threadIdx.x - off] : 0u;
        __syncthreads();
        sh[threadIdx.x] += t;
        __syncthreads();
    }
    if (threadIdx.x < (unsigned)m) p[threadIdx.x] = sh[threadIdx.x] - v;  // exclusive
}

// A-part: rp8/pos8 over [0, mA]; B-part: rpf over [0, n]. One launch.
__global__ void scan_add_kernel(unsigned* __restrict__ rp8, unsigned* __restrict__ pos8,
                                const unsigned* __restrict__ pA, unsigned* __restrict__ rpf,
                                const unsigned* __restrict__ pB, int mA, int n, int e) {
    int i = blockIdx.x * blockDim.x + threadIdx.x;
    if (i < mA) {
        unsigned v = rp8[i] + pA[i >> 10];
        rp8[i] = v;
        pos8[i] = v;
    } else if (i == mA) {
        rp8[mA] = (unsigned)e;
    }
    int j = i - (mA + 1);
    if (j >= 0) {
        if (j < n) rpf[j] += pB[j >> 10];
        else if (j == n) rpf[n] = (unsigned)e;
    }
}

// ---- fill: XCD-local append. csr8[slot] = src | (bf16(norm) << 16) ----
// 1 edge/thread (atomic-latency bound: needs max TLP). Regular stores (L2 merge).
__global__ void fill_kernel(const int* __restrict__ src, const int* __restrict__ dst,
                            const float* __restrict__ dinv, unsigned* __restrict__ pos8,
                            unsigned* __restrict__ csr8, int n, int e) {
    int t = blockIdx.x * blockDim.x + threadIdx.x;
    if (t >= e) return;
    int x = blockIdx.x & 7;  // MUST match degree8_kernel's formula
    int s = src[t], d = dst[t];
    float norm = dinv[s] * dinv[d];                                  // in (0, 1]
    unsigned nb = (__float_as_uint(norm) + 0x8000u) & 0xffff0000u;   // round-to-nearest bf16
    unsigned idx = atomicAdd(&pos8[x * n + d], 1u);
    csr8[idx] = nb | (unsigned)s;
}

// ---- compact: concatenate each node's 8 segments -> node-major csr ----
__global__ void compact_kernel(const unsigned* __restrict__ csr8, const unsigned* __restrict__ rp8,
                               const unsigned* __restrict__ rpf, unsigned* __restrict__ csr, int n) {
    int lane = threadIdx.x & 63;
    int row = blockIdx.x * 4 + (threadIdx.x >> 6);  // one wave per node
    if (row >= n) return;
    unsigned st = 0, len = 0;
    if (lane < 8) {
        st = rp8[lane * n + row];
        len = rp8[lane * n + row + 1] - st;  // valid in flattened x-major scan
    }
    unsigned base = rpf[row];
    unsigned pre = 0;
#pragma unroll
    for (int x = 0; x < 8; ++x) {
        unsigned sx = __shfl(st, x);
        unsigned lx = __shfl(len, x);
        for (unsigned k = lane; k < lx; k += 64)
            csr[base + pre + k] = csr8[sx + k];
        pre += lx;
    }
}

// ---- Yh[n,64] (fp16) = f(X[n,64]) @ W[64,64]; 16 lanes/row, 4 rows/wave ----
__global__ void gemm64_kernel(const float4* __restrict__ X4, const float* __restrict__ W,
                              const float* __restrict__ bias, int do_relu,
                              __half* __restrict__ Yh, int n) {
    __shared__ float4 Ws[64][16];  // Ws[k][l] = W[k][4l..4l+3]
    for (int i = threadIdx.x; i < 64 * 16; i += blockDim.x)
        Ws[i >> 4][i & 15] = ((const float4*)W)[i];
    __syncthreads();
    int lane = threadIdx.x & 63;
    int l = lane & 15;
    int gbase = lane & 48;
    int wid = blockIdx.x * (blockDim.x >> 6) + (threadIdx.x >> 6);
    int row = wid * 4 + (lane >> 4);
    if (row >= n) return;
    float4 xv = X4[(size_t)row * 16 + l];
    if (bias) {
        float4 b = ((const float4*)bias)[l];
        xv.x += b.x; xv.y += b.y; xv.z += b.z; xv.w += b.w;
    }
    if (do_relu) {
        xv.x = fmaxf(xv.x, 0.f); xv.y = fmaxf(xv.y, 0.f);
        xv.z = fmaxf(xv.z, 0.f); xv.w = fmaxf(xv.w, 0.f);
    }
    float4 acc = make_float4(0.f, 0.f, 0.f, 0.f);
#pragma unroll
    for (int k = 0; k < 64; ++k) {
        float comp = (k & 3) == 0 ? xv.x : (k & 3) == 1 ? xv.y : (k & 3) == 2 ? xv.z : xv.w;
        float a = __shfl(comp, gbase + (k >> 2));
        float4 w = Ws[k][l];
        acc.x = fmaf(a, w.x, acc.x); acc.y = fmaf(a, w.y, acc.y);
        acc.z = fmaf(a, w.z, acc.z); acc.w = fmaf(a, w.w, acc.w);
    }
    __half2 h0 = __floats2half2_rn(acc.x, acc.y);
    __half2 h1 = __floats2half2_rn(acc.z, acc.w);
    uint2 o;
    o.x = *(const unsigned*)&h0;
    o.y = *(const unsigned*)&h1;
    *(uint2*)(Yh + (size_t)row * 64 + 4 * l) = o;
}

// ---- gather (32-col half): 16-lane group per dst node; lane l owns cols
// colbase+2l .. colbase+2l+1. Per-edge read = one 64 B line (half-row),
// per-pass xwh footprint 3.2 MB -> XCD-L2 resident. Output NT (full-line). ----
__global__ void gather_half_kernel(const __half* __restrict__ xwh, const unsigned* __restrict__ csr,
                                   const unsigned* __restrict__ row_ptr, const float* __restrict__ dinv,
                                   const float* __restrict__ bias, float* __restrict__ out,
                                   int n, int colbase) {
    int lane = threadIdx.x & 63;
    int l = lane & 15;
    int gbase = lane & 48;
    int wid = blockIdx.x * (blockDim.x >> 6) + (threadIdx.x >> 6);
    int row = wid * 4 + (lane >> 4);
    if (row >= n) return;  // 16-lane group exits together; shfl stays in-group
    unsigned start = row_ptr[row], end = row_ptr[row + 1];
    float di = dinv[row];
    float s2 = di * di;
    float2 acc;
    {   // self-loop term
        __half2 hv = *(const __half2*)(xwh + (size_t)row * 64 + colbase + 2 * l);
        float2 f = __half22float2(hv);
        acc = make_float2(f.x * s2, f.y * s2);
    }
    if (bias) {
        float2 b = ((const float2*)(bias + colbase))[l];
        acc.x += b.x; acc.y += b.y;
    }
    for (unsigned base = start; base < end; base += 16) {
        int j = (int)(base + (unsigned)l);
        unsigned ed = (j < (int)end) ? __builtin_nontemporal_load(&csr[j]) : 0u;
        int cnt = (int)min(16u, end - base);
#pragma unroll
        for (int t = 0; t < 16; ++t) {
            unsigned p = __shfl(ed, gbase + t);
            int st = (int)(p & 0xffffu);                   // src (< 2^16: safe)
            float nrm = __uint_as_float(p & 0xffff0000u);  // bf16 -> f32 = mask
            nrm = (t < cnt) ? nrm : 0.0f;                  // predicate tail
            __half2 hv = *(const __half2*)(xwh + (size_t)st * 64 + colbase + 2 * l);
            float2 f = __half22float2(hv);
            acc.x = fmaf(nrm, f.x, acc.x);
            acc.y = fmaf(nrm, f.y, acc.y);
        }
    }
    // NT store: full-line wave-contiguous output, keep xwh half resident in L2.
    float2* op = (float2*)(out + (size_t)row * 64 + colbase + 2 * l);
    __builtin_nontemporal_store(acc.x, &op->x);
    __builtin_nontemporal_store(acc.y, &op->y);
}

extern "C" void kernel_launch(void* const* d_in, const int* in_sizes, int n_in,
                              void* d_out, int out_size, void* d_ws, size_t ws_size,
                              hipStream_t stream) {
    const float* x  = (const float*)d_in[0];
    const int*   ei = (const int*)d_in[1];
    const float* W1 = (const float*)d_in[2];
    const float* b1 = (const float*)d_in[3];
    const float* W2 = (const float*)d_in[4];
    const float* b2 = (const float*)d_in[5];
    const int n = in_sizes[0] / 64;   // 50000 (packed-csr path requires <= 65535)
    const int e = in_sizes[1] / 2;    // 1600000
    const int* src = ei;              // edge_index[0]
    const int* dst = ei + e;          // edge_index[1]

    char* ws = (char*)d_ws;
    size_t off = 0;
    auto alloc = [&](size_t bytes) -> void* {
        void* p = ws + off;
        off = (off + bytes + 255) & ~(size_t)255;
        return p;
    };
    unsigned* deg8      = (unsigned*)alloc((size_t)8 * n * 4);       // 1.6 MB
    unsigned* rp8       = (unsigned*)alloc(((size_t)8 * n + 1) * 4); // 1.6 MB
    unsigned* pos8      = (unsigned*)alloc((size_t)8 * n * 4);       // 1.6 MB
    unsigned* partialsA = (unsigned*)alloc(1024 * 4);
    unsigned* partialsB = (unsigned*)alloc(1024 * 4);
    unsigned* rpf       = (unsigned*)alloc((size_t)(n + 1) * 4);
    float*    dinv      = (float*)alloc((size_t)n * 4);
    unsigned* csr       = (unsigned*)alloc((size_t)e * 4);           // 6.4 MB node-major
    // csr8 dead after compact; xwh (fp16, 6.4 MB) overlays it.
    size_t ov = (size_t)e * 4 > (size_t)n * 64 * 2 ? (size_t)e * 4 : (size_t)n * 64 * 2;
    char*     overlay   = (char*)alloc(ov);
    unsigned* csr8      = (unsigned*)overlay;
    __half*   xwh       = (__half*)overlay;
    float*    agg       = (float*)alloc((size_t)n * 64 * 4);         // 12.8 MB
    float*    outf      = (float*)d_out;

    const int mA = 8 * n;                    // 400000
    const int nbA = (mA + 1023) / 1024;      // 391
    const int nbB = (n + 1023) / 1024;       // 49

    // CSR build (shared by both layers)
    hipMemsetAsync(deg8, 0, (size_t)mA * 4, stream);
    degree8_kernel<<<(e + 255) / 256, 256, 0, stream>>>(dst, deg8, n, e);
    scanA_local<<<nbA, 1024, 0, stream>>>(deg8, rp8, partialsA, mA);
    scanB_local<<<nbB, 1024, 0, stream>>>(deg8, rpf, partialsB, dinv, n);
    scan_partials_both<<<2, 1024, 0, stream>>>(partialsA, nbA, partialsB, nbB);
    scan_add_kernel<<<(mA + n + 2 + 255) / 256, 256, 0, stream>>>(rp8, pos8, partialsA,
                                                                  rpf, partialsB, mA, n, e);
    fill_kernel<<<(e + 255) / 256, 256, 0, stream>>>(src, dst, dinv, pos8, csr8, n, e);
    compact_kernel<<<(n + 3) / 4, 256, 0, stream>>>(csr8, rp8, rpf, csr, n);

    const int gblocks = (n + 15) / 16;

    // layer 1: xwh = fp16(x @ W1) ; agg = A_hat-gather(xwh)   (xwh overwrites dead csr8)
    gemm64_kernel<<<gblocks, 256, 0, stream>>>((const float4*)x, W1, nullptr, 0, xwh, n);
    gather_half_kernel<<<gblocks, 256, 0, stream>>>(xwh, csr, rpf, dinv, nullptr, agg, n, 0);
    gather_half_kernel<<<gblocks, 256, 0, stream>>>(xwh, csr, rpf, dinv, nullptr, agg, n, 32);

    // layer 2: xwh = fp16(relu(agg + b1) @ W2) ; out = A_hat-gather(xwh) + b2
    gemm64_kernel<<<gblocks, 256, 0, stream>>>((const float4*)agg, W2, b1, 1, xwh, n);
    gather_half_kernel<<<gblocks, 256, 0, stream>>>(xwh, csr, rpf, dinv, b2, outf, n, 0);
    gather_half_kernel<<<gblocks, 256, 0, stream>>>(xwh, csr, rpf, dinv, b2, outf, n, 32);
}

// Round 7
// 345.270 us; speedup vs baseline: 1.1046x; 1.1046x over previous
//
#include <hip/hip_runtime.h>
#include <hip/hip_fp16.h>

// GCN 2-layer: out = A_hat @ relu(A_hat @ (X W1) + b1) W2 + b2
// A_hat = D^-1/2 (A+I) D^-1/2.
// R7 = best-measured recombination:
//   - build: R4/R6 XCD-bucketed fill, 1 edge/thread (68 us measured; 4x-ILP
//     variant regressed to 118 us — atomic-latency bound, needs TLP not ILP).
//   - gather: R5 combined fp16 uint2 row reads (R6's split-feature 2-pass
//     FAILED +80 us: per-edge line count unchanged, inst count doubled).

// ---- degree, bucketed by x = blockIdx&7 (256 edges per block) ----
__global__ void degree8_kernel(const int* __restrict__ dst, unsigned* __restrict__ deg8,
                               int n, int e) {
    int t = blockIdx.x * blockDim.x + threadIdx.x;
    if (t >= e) return;
    int x = blockIdx.x & 7;
    atomicAdd(&deg8[x * n + dst[t]], 1u);
}

// ---- block scans ----
__global__ void scanA_local(const unsigned* __restrict__ deg8, unsigned* __restrict__ rp8,
                            unsigned* __restrict__ partials, int m) {
    __shared__ unsigned sh[1024];
    int i = blockIdx.x * 1024 + threadIdx.x;
    unsigned v = (i < m) ? deg8[i] : 0u;
    sh[threadIdx.x] = v;
    __syncthreads();
    for (int off = 1; off < 1024; off <<= 1) {
        unsigned t = (threadIdx.x >= (unsigned)off) ? sh[threadIdx.x - off] : 0u;
        __syncthreads();
        sh[threadIdx.x] += t;
        __syncthreads();
    }
    if (i < m) rp8[i] = sh[threadIdx.x] - v;  // exclusive
    if (threadIdx.x == 1023) partials[blockIdx.x] = sh[1023];
}

// node-total degrees -> rpf (pre-add); dinv fused
__global__ void scanB_local(const unsigned* __restrict__ deg8, unsigned* __restrict__ rpf,
                            unsigned* __restrict__ partials, float* __restrict__ dinv, int n) {
    __shared__ unsigned sh[1024];
    int i = blockIdx.x * 1024 + threadIdx.x;
    unsigned v = 0;
    if (i < n) {
#pragma unroll
        for (int x = 0; x < 8; ++x) v += deg8[x * n + i];
        dinv[i] = rsqrtf((float)v + 1.0f);  // +1 self-loop; always > 0
    }
    sh[threadIdx.x] = v;
    __syncthreads();
    for (int off = 1; off < 1024; off <<= 1) {
        unsigned t = (threadIdx.x >= (unsigned)off) ? sh[threadIdx.x - off] : 0u;
        __syncthreads();
        sh[threadIdx.x] += t;
        __syncthreads();
    }
    if (i < n) rpf[i] = sh[threadIdx.x] - v;  // exclusive
    if (threadIdx.x == 1023) partials[blockIdx.x] = sh[1023];
}

// block 0 scans partialsA[mA_], block 1 scans partialsB[mB_] (both <= 1024)
__global__ void scan_partials_both(unsigned* __restrict__ pA, int mA_,
                                   unsigned* __restrict__ pB, int mB_) {
    __shared__ unsigned sh[1024];
    unsigned* p = blockIdx.x ? pB : pA;
    int m = blockIdx.x ? mB_ : mA_;
    unsigned v = (threadIdx.x < (unsigned)m) ? p[threadIdx.x] : 0u;
    sh[threadIdx.x] = v;
    __syncthreads();
    for (int off = 1; off < 1024; off <<= 1) {
        unsigned t = (threadIdx.x >= (unsigned)off) ? sh[threadIdx.x - off] : 0u;
        __syncthreads();
        sh[threadIdx.x] += t;
        __syncthreads();
    }
    if (threadIdx.x < (unsigned)m) p[threadIdx.x] = sh[threadIdx.x] - v;  // exclusive
}

// A-part: rp8/pos8 over [0, mA]; B-part: rpf over [0, n]. One launch.
__global__ void scan_add_kernel(unsigned* __restrict__ rp8, unsigned* __restrict__ pos8,
                                const unsigned* __restrict__ pA, unsigned* __restrict__ rpf,
                                const unsigned* __restrict__ pB, int mA, int n, int e) {
    int i = blockIdx.x * blockDim.x + threadIdx.x;
    if (i < mA) {
        unsigned v = rp8[i] + pA[i >> 10];
        rp8[i] = v;
        pos8[i] = v;
    } else if (i == mA) {
        rp8[mA] = (unsigned)e;
    }
    int j = i - (mA + 1);
    if (j >= 0) {
        if (j < n) rpf[j] += pB[j >> 10];
        else if (j == n) rpf[n] = (unsigned)e;
    }
}

// ---- fill: XCD-local append. csr8[slot] = src | (bf16(norm) << 16) ----
// 1 edge/thread (atomic-latency bound: needs max TLP). Regular stores (L2 merge).
__global__ void fill_kernel(const int* __restrict__ src, const int* __restrict__ dst,
                            const float* __restrict__ dinv, unsigned* __restrict__ pos8,
                            unsigned* __restrict__ csr8, int n, int e) {
    int t = blockIdx.x * blockDim.x + threadIdx.x;
    if (t >= e) return;
    int x = blockIdx.x & 7;  // MUST match degree8_kernel's formula
    int s = src[t], d = dst[t];
    float norm = dinv[s] * dinv[d];                                  // in (0, 1]
    unsigned nb = (__float_as_uint(norm) + 0x8000u) & 0xffff0000u;   // round-to-nearest bf16
    unsigned idx = atomicAdd(&pos8[x * n + d], 1u);
    csr8[idx] = nb | (unsigned)s;
}

// ---- compact: concatenate each node's 8 segments -> node-major csr ----
__global__ void compact_kernel(const unsigned* __restrict__ csr8, const unsigned* __restrict__ rp8,
                               const unsigned* __restrict__ rpf, unsigned* __restrict__ csr, int n) {
    int lane = threadIdx.x & 63;
    int row = blockIdx.x * 4 + (threadIdx.x >> 6);  // one wave per node
    if (row >= n) return;
    unsigned st = 0, len = 0;
    if (lane < 8) {
        st = rp8[lane * n + row];
        len = rp8[lane * n + row + 1] - st;  // valid in flattened x-major scan
    }
    unsigned base = rpf[row];
    unsigned pre = 0;
#pragma unroll
    for (int x = 0; x < 8; ++x) {
        unsigned sx = __shfl(st, x);
        unsigned lx = __shfl(len, x);
        for (unsigned k = lane; k < lx; k += 64)
            csr[base + pre + k] = csr8[sx + k];
        pre += lx;
    }
}

// ---- Yh[n,64] (fp16) = f(X[n,64]) @ W[64,64]; 16 lanes/row, 4 rows/wave ----
__global__ void gemm64_kernel(const float4* __restrict__ X4, const float* __restrict__ W,
                              const float* __restrict__ bias, int do_relu,
                              __half* __restrict__ Yh, int n) {
    __shared__ float4 Ws[64][16];  // Ws[k][l] = W[k][4l..4l+3]
    for (int i = threadIdx.x; i < 64 * 16; i += blockDim.x)
        Ws[i >> 4][i & 15] = ((const float4*)W)[i];
    __syncthreads();
    int lane = threadIdx.x & 63;
    int l = lane & 15;
    int gbase = lane & 48;
    int wid = blockIdx.x * (blockDim.x >> 6) + (threadIdx.x >> 6);
    int row = wid * 4 + (lane >> 4);
    if (row >= n) return;
    float4 xv = X4[(size_t)row * 16 + l];
    if (bias) {
        float4 b = ((const float4*)bias)[l];
        xv.x += b.x; xv.y += b.y; xv.z += b.z; xv.w += b.w;
    }
    if (do_relu) {
        xv.x = fmaxf(xv.x, 0.f); xv.y = fmaxf(xv.y, 0.f);
        xv.z = fmaxf(xv.z, 0.f); xv.w = fmaxf(xv.w, 0.f);
    }
    float4 acc = make_float4(0.f, 0.f, 0.f, 0.f);
#pragma unroll
    for (int k = 0; k < 64; ++k) {
        float comp = (k & 3) == 0 ? xv.x : (k & 3) == 1 ? xv.y : (k & 3) == 2 ? xv.z : xv.w;
        float a = __shfl(comp, gbase + (k >> 2));
        float4 w = Ws[k][l];
        acc.x = fmaf(a, w.x, acc.x); acc.y = fmaf(a, w.y, acc.y);
        acc.z = fmaf(a, w.z, acc.z); acc.w = fmaf(a, w.w, acc.w);
    }
    __half2 h0 = __floats2half2_rn(acc.x, acc.y);
    __half2 h1 = __floats2half2_rn(acc.z, acc.w);
    uint2 o;
    o.x = *(const unsigned*)&h0;
    o.y = *(const unsigned*)&h1;
    *(uint2*)(Yh + (size_t)row * 64 + 4 * l) = o;
}

// ---- gather: 16-lane group per dst node; lane l owns cols 4l..4l+3 (fp16 xw) ----
__global__ void gather_kernel(const __half* __restrict__ xwh, const unsigned* __restrict__ csr,
                              const unsigned* __restrict__ row_ptr, const float* __restrict__ dinv,
                              const float* __restrict__ bias, float4* __restrict__ out4, int n) {
    int lane = threadIdx.x & 63;
    int l = lane & 15;
    int gbase = lane & 48;
    int wid = blockIdx.x * (blockDim.x >> 6) + (threadIdx.x >> 6);
    int row = wid * 4 + (lane >> 4);
    if (row >= n) return;  // 16-lane group exits together; shfl stays in-group
    unsigned start = row_ptr[row], end = row_ptr[row + 1];
    float di = dinv[row];
    float s2 = di * di;
    float4 acc;
    {   // self-loop term
        uint2 hv = *(const uint2*)(xwh + (size_t)row * 64 + 4 * l);
        float2 f0 = __half22float2(*(const __half2*)&hv.x);
        float2 f1 = __half22float2(*(const __half2*)&hv.y);
        acc = make_float4(f0.x * s2, f0.y * s2, f1.x * s2, f1.y * s2);
    }
    if (bias) {
        float4 b = ((const float4*)bias)[l];
        acc.x += b.x; acc.y += b.y; acc.z += b.z; acc.w += b.w;
    }
    for (unsigned base = start; base < end; base += 16) {
        int j = (int)(base + (unsigned)l);
        unsigned ed = (j < (int)end) ? __builtin_nontemporal_load(&csr[j]) : 0u;
        int cnt = (int)min(16u, end - base);
#pragma unroll
        for (int t = 0; t < 16; ++t) {
            unsigned p = __shfl(ed, gbase + t);
            int st = (int)(p & 0xffffu);                   // src (< 2^16: safe)
            float nrm = __uint_as_float(p & 0xffff0000u);  // bf16 -> f32 = mask
            nrm = (t < cnt) ? nrm : 0.0f;                  // predicate tail
            uint2 hv = *(const uint2*)(xwh + (size_t)st * 64 + 4 * l);
            float2 f0 = __half22float2(*(const __half2*)&hv.x);
            float2 f1 = __half22float2(*(const __half2*)&hv.y);
            acc.x = fmaf(nrm, f0.x, acc.x); acc.y = fmaf(nrm, f0.y, acc.y);
            acc.z = fmaf(nrm, f1.x, acc.z); acc.w = fmaf(nrm, f1.y, acc.w);
        }
    }
    out4[(size_t)row * 16 + l] = acc;
}

extern "C" void kernel_launch(void* const* d_in, const int* in_sizes, int n_in,
                              void* d_out, int out_size, void* d_ws, size_t ws_size,
                              hipStream_t stream) {
    const float* x  = (const float*)d_in[0];
    const int*   ei = (const int*)d_in[1];
    const float* W1 = (const float*)d_in[2];
    const float* b1 = (const float*)d_in[3];
    const float* W2 = (const float*)d_in[4];
    const float* b2 = (const float*)d_in[5];
    const int n = in_sizes[0] / 64;   // 50000 (packed-csr path requires <= 65535)
    const int e = in_sizes[1] / 2;    // 1600000
    const int* src = ei;              // edge_index[0]
    const int* dst = ei + e;          // edge_index[1]

    char* ws = (char*)d_ws;
    size_t off = 0;
    auto alloc = [&](size_t bytes) -> void* {
        void* p = ws + off;
        off = (off + bytes + 255) & ~(size_t)255;
        return p;
    };
    unsigned* deg8      = (unsigned*)alloc((size_t)8 * n * 4);       // 1.6 MB
    unsigned* rp8       = (unsigned*)alloc(((size_t)8 * n + 1) * 4); // 1.6 MB
    unsigned* pos8      = (unsigned*)alloc((size_t)8 * n * 4);       // 1.6 MB
    unsigned* partialsA = (unsigned*)alloc(1024 * 4);
    unsigned* partialsB = (unsigned*)alloc(1024 * 4);
    unsigned* rpf       = (unsigned*)alloc((size_t)(n + 1) * 4);
    float*    dinv      = (float*)alloc((size_t)n * 4);
    unsigned* csr       = (unsigned*)alloc((size_t)e * 4);           // 6.4 MB node-major
    // csr8 dead after compact; xwh (fp16, 6.4 MB) overlays it.
    size_t ov = (size_t)e * 4 > (size_t)n * 64 * 2 ? (size_t)e * 4 : (size_t)n * 64 * 2;
    char*     overlay   = (char*)alloc(ov);
    unsigned* csr8      = (unsigned*)overlay;
    __half*   xwh       = (__half*)overlay;
    float*    agg       = (float*)alloc((size_t)n * 64 * 4);         // 12.8 MB
    float*    outf      = (float*)d_out;

    const int mA = 8 * n;                    // 400000
    const int nbA = (mA + 1023) / 1024;      // 391
    const int nbB = (n + 1023) / 1024;       // 49

    // CSR build (shared by both layers)
    hipMemsetAsync(deg8, 0, (size_t)mA * 4, stream);
    degree8_kernel<<<(e + 255) / 256, 256, 0, stream>>>(dst, deg8, n, e);
    scanA_local<<<nbA, 1024, 0, stream>>>(deg8, rp8, partialsA, mA);
    scanB_local<<<nbB, 1024, 0, stream>>>(deg8, rpf, partialsB, dinv, n);
    scan_partials_both<<<2, 1024, 0, stream>>>(partialsA, nbA, partialsB, nbB);
    scan_add_kernel<<<(mA + n + 2 + 255) / 256, 256, 0, stream>>>(rp8, pos8, partialsA,
                                                                  rpf, partialsB, mA, n, e);
    fill_kernel<<<(e + 255) / 256, 256, 0, stream>>>(src, dst, dinv, pos8, csr8, n, e);
    compact_kernel<<<(n + 3) / 4, 256, 0, stream>>>(csr8, rp8, rpf, csr, n);

    const int gblocks = (n + 15) / 16;

    // layer 1: xwh = fp16(x @ W1) ; agg = A_hat-gather(xwh)   (xwh overwrites dead csr8)
    gemm64_kernel<<<gblocks, 256, 0, stream>>>((const float4*)x, W1, nullptr, 0, xwh, n);
    gather_kernel<<<gblocks, 256, 0, stream>>>(xwh, csr, rpf, dinv, nullptr, (float4*)agg, n);

    // layer 2: xwh = fp16(relu(agg + b1) @ W2) ; out = A_hat-gather(xwh) + b2
    gemm64_kernel<<<gblocks, 256, 0, stream>>>((const float4*)agg, W2, b1, 1, xwh, n);
    gather_kernel<<<gblocks, 256, 0, stream>>>(xwh, csr, rpf, dinv, b2, (float4*)outf, n);
}

// Round 8
// 298.319 us; speedup vs baseline: 1.2784x; 1.1574x over previous
//
#include <hip/hip_runtime.h>
#include <hip/hip_fp16.h>

// GCN 2-layer: out = A_hat @ relu(A_hat @ (X W1) + b1) W2 + b2
// A_hat = D^-1/2 (A+I) D^-1/2.
// R8: two-phase dst-range-bucketed CSR build. R7's fill wrote 62 MB at
// 0.93 TB/s (random partial-line HBM RMW ceiling) because blockIdx&7 gives no
// real line ownership. Now: (1) bucket edges by dst>>9 into ebuf whose bucket
// regions coincide with final csr regions (cursor=rpf[512k]); per-(block,
// bucket) contiguous runs via LDS hist + one global atomic. (2) per-bucket
// block: LDS pos[512] counters, writes confined to a 64 KB csr window in ONE
// XCD's L2 -> full-line writebacks. Gather/gemm identical to R7 (proven).

// ---- degree (single array; 8-way bucketing obsolete) ----
__global__ void degree_kernel(const int* __restrict__ dst, unsigned* __restrict__ deg, int e) {
    int t = blockIdx.x * blockDim.x + threadIdx.x;
    if (t < e) atomicAdd(&deg[dst[t]], 1u);
}

// ---- exclusive scan of deg -> rpf (pre-add); dinv fused ----
__global__ void scan_local(const unsigned* __restrict__ deg, unsigned* __restrict__ rpf,
                           unsigned* __restrict__ partials, float* __restrict__ dinv, int n) {
    __shared__ unsigned sh[1024];
    int i = blockIdx.x * 1024 + threadIdx.x;
    unsigned v = (i < n) ? deg[i] : 0u;
    if (i < n) dinv[i] = rsqrtf((float)v + 1.0f);  // +1 self-loop; always > 0
    sh[threadIdx.x] = v;
    __syncthreads();
    for (int off = 1; off < 1024; off <<= 1) {
        unsigned t = (threadIdx.x >= (unsigned)off) ? sh[threadIdx.x - off] : 0u;
        __syncthreads();
        sh[threadIdx.x] += t;
        __syncthreads();
    }
    if (i < n) rpf[i] = sh[threadIdx.x] - v;  // exclusive
    if (threadIdx.x == 1023) partials[blockIdx.x] = sh[1023];
}

__global__ void scan_partials(unsigned* __restrict__ p, int m) {
    __shared__ unsigned sh[1024];
    unsigned v = (threadIdx.x < (unsigned)m) ? p[threadIdx.x] : 0u;
    sh[threadIdx.x] = v;
    __syncthreads();
    for (int off = 1; off < 1024; off <<= 1) {
        unsigned t = (threadIdx.x >= (unsigned)off) ? sh[threadIdx.x - off] : 0u;
        __syncthreads();
        sh[threadIdx.x] += t;
        __syncthreads();
    }
    if (threadIdx.x < (unsigned)m) p[threadIdx.x] = sh[threadIdx.x] - v;  // exclusive
}

// finalize rpf; also emit bucket cursors (= final rpf at window starts)
__global__ void scan_add_kernel(unsigned* __restrict__ rpf, const unsigned* __restrict__ partials,
                                unsigned* __restrict__ cursor, int n, int e) {
    int i = blockIdx.x * blockDim.x + threadIdx.x;
    if (i < n) {
        unsigned v = rpf[i] + partials[i >> 10];
        rpf[i] = v;
        if ((i & 511) == 0) cursor[i >> 9] = v;
    } else if (i == n) {
        rpf[n] = (unsigned)e;
    }
}

// ---- phase 1: bucket edges by dst>>9. ebuf[slot] = dst<<16 | src ----
// Per-(block,bucket) contiguous run: LDS hist -> one global atomic -> place.
#define P1_EDGES 4096
__global__ void bucket_kernel(const int* __restrict__ src, const int* __restrict__ dst,
                              unsigned* __restrict__ cursor, unsigned* __restrict__ ebuf,
                              int e, int B) {
    __shared__ unsigned hist[128];
    __shared__ unsigned base[128];
    for (int i = threadIdx.x; i < B; i += 1024) hist[i] = 0;
    __syncthreads();
    int e0 = blockIdx.x * P1_EDGES;
    unsigned bk[4], rk[4], pk[4];
    int cnt = 0;
#pragma unroll
    for (int k = 0; k < 4; ++k) {
        int t = e0 + k * 1024 + threadIdx.x;  // strided: coalesced reads
        if (t < e) {
            unsigned s = (unsigned)src[t], d = (unsigned)dst[t];
            unsigned b = d >> 9;
            bk[cnt] = b;
            rk[cnt] = atomicAdd(&hist[b], 1u);   // rank within (block,bucket)
            pk[cnt] = (d << 16) | s;             // n < 2^16: both fit
            cnt++;
        }
    }
    __syncthreads();
    for (int i = threadIdx.x; i < B; i += 1024)
        base[i] = hist[i] ? atomicAdd(&cursor[i], hist[i]) : 0u;
    __syncthreads();
    for (int k = 0; k < cnt; ++k)
        ebuf[base[bk[k]] + rk[k]] = pk[k];
}

// ---- phase 2: per-bucket fill. One block per 512-node window; LDS pos
// counters; csr writes land in a ~64 KB window inside one XCD's L2. ----
__global__ void sortfill_kernel(const unsigned* __restrict__ ebuf, const unsigned* __restrict__ rpf,
                                const float* __restrict__ dinv, unsigned* __restrict__ csr, int n) {
    __shared__ unsigned pos[512];
    __shared__ unsigned rpl[512];
    __shared__ float dl[512];
    int w0 = blockIdx.x << 9;
    int w1 = min(w0 + 512, n);
    int wlen = w1 - w0;
    for (int i = threadIdx.x; i < 512; i += 1024) {
        pos[i] = 0;
        if (i < wlen) {
            rpl[i] = rpf[w0 + i];
            dl[i] = dinv[w0 + i];
        }
    }
    __syncthreads();
    unsigned start = rpf[w0], end = rpf[w1];
    for (unsigned j = start + threadIdx.x; j < end; j += 1024) {
        unsigned p = ebuf[j];
        unsigned d = p >> 16;
        unsigned s = p & 0xffffu;
        float norm = dinv[s] * dl[d - w0];                              // in (0, 1]
        unsigned nb = (__float_as_uint(norm) + 0x8000u) & 0xffff0000u;  // rn bf16
        unsigned r = atomicAdd(&pos[d - w0], 1u);
        csr[rpl[d - w0] + r] = nb | s;
    }
}

// ---- Yh[n,64] (fp16) = f(X[n,64]) @ W[64,64]; 16 lanes/row, 4 rows/wave ----
__global__ void gemm64_kernel(const float4* __restrict__ X4, const float* __restrict__ W,
                              const float* __restrict__ bias, int do_relu,
                              __half* __restrict__ Yh, int n) {
    __shared__ float4 Ws[64][16];  // Ws[k][l] = W[k][4l..4l+3]
    for (int i = threadIdx.x; i < 64 * 16; i += blockDim.x)
        Ws[i >> 4][i & 15] = ((const float4*)W)[i];
    __syncthreads();
    int lane = threadIdx.x & 63;
    int l = lane & 15;
    int gbase = lane & 48;
    int wid = blockIdx.x * (blockDim.x >> 6) + (threadIdx.x >> 6);
    int row = wid * 4 + (lane >> 4);
    if (row >= n) return;
    float4 xv = X4[(size_t)row * 16 + l];
    if (bias) {
        float4 b = ((const float4*)bias)[l];
        xv.x += b.x; xv.y += b.y; xv.z += b.z; xv.w += b.w;
    }
    if (do_relu) {
        xv.x = fmaxf(xv.x, 0.f); xv.y = fmaxf(xv.y, 0.f);
        xv.z = fmaxf(xv.z, 0.f); xv.w = fmaxf(xv.w, 0.f);
    }
    float4 acc = make_float4(0.f, 0.f, 0.f, 0.f);
#pragma unroll
    for (int k = 0; k < 64; ++k) {
        float comp = (k & 3) == 0 ? xv.x : (k & 3) == 1 ? xv.y : (k & 3) == 2 ? xv.z : xv.w;
        float a = __shfl(comp, gbase + (k >> 2));
        float4 w = Ws[k][l];
        acc.x = fmaf(a, w.x, acc.x); acc.y = fmaf(a, w.y, acc.y);
        acc.z = fmaf(a, w.z, acc.z); acc.w = fmaf(a, w.w, acc.w);
    }
    __half2 h0 = __floats2half2_rn(acc.x, acc.y);
    __half2 h1 = __floats2half2_rn(acc.z, acc.w);
    uint2 o;
    o.x = *(const unsigned*)&h0;
    o.y = *(const unsigned*)&h1;
    *(uint2*)(Yh + (size_t)row * 64 + 4 * l) = o;
}

// ---- gather: 16-lane group per dst node; lane l owns cols 4l..4l+3 (fp16 xw) ----
__global__ void gather_kernel(const __half* __restrict__ xwh, const unsigned* __restrict__ csr,
                              const unsigned* __restrict__ row_ptr, const float* __restrict__ dinv,
                              const float* __restrict__ bias, float4* __restrict__ out4, int n) {
    int lane = threadIdx.x & 63;
    int l = lane & 15;
    int gbase = lane & 48;
    int wid = blockIdx.x * (blockDim.x >> 6) + (threadIdx.x >> 6);
    int row = wid * 4 + (lane >> 4);
    if (row >= n) return;  // 16-lane group exits together; shfl stays in-group
    unsigned start = row_ptr[row], end = row_ptr[row + 1];
    float di = dinv[row];
    float s2 = di * di;
    float4 acc;
    {   // self-loop term
        uint2 hv = *(const uint2*)(xwh + (size_t)row * 64 + 4 * l);
        float2 f0 = __half22float2(*(const __half2*)&hv.x);
        float2 f1 = __half22float2(*(const __half2*)&hv.y);
        acc = make_float4(f0.x * s2, f0.y * s2, f1.x * s2, f1.y * s2);
    }
    if (bias) {
        float4 b = ((const float4*)bias)[l];
        acc.x += b.x; acc.y += b.y; acc.z += b.z; acc.w += b.w;
    }
    for (unsigned base = start; base < end; base += 16) {
        int j = (int)(base + (unsigned)l);
        unsigned ed = (j < (int)end) ? __builtin_nontemporal_load(&csr[j]) : 0u;
        int cnt = (int)min(16u, end - base);
#pragma unroll
        for (int t = 0; t < 16; ++t) {
            unsigned p = __shfl(ed, gbase + t);
            int st = (int)(p & 0xffffu);                   // src (< 2^16: safe)
            float nrm = __uint_as_float(p & 0xffff0000u);  // bf16 -> f32 = mask
            nrm = (t < cnt) ? nrm : 0.0f;                  // predicate tail
            uint2 hv = *(const uint2*)(xwh + (size_t)st * 64 + 4 * l);
            float2 f0 = __half22float2(*(const __half2*)&hv.x);
            float2 f1 = __half22float2(*(const __half2*)&hv.y);
            acc.x = fmaf(nrm, f0.x, acc.x); acc.y = fmaf(nrm, f0.y, acc.y);
            acc.z = fmaf(nrm, f1.x, acc.z); acc.w = fmaf(nrm, f1.y, acc.w);
        }
    }
    out4[(size_t)row * 16 + l] = acc;
}

extern "C" void kernel_launch(void* const* d_in, const int* in_sizes, int n_in,
                              void* d_out, int out_size, void* d_ws, size_t ws_size,
                              hipStream_t stream) {
    const float* x  = (const float*)d_in[0];
    const int*   ei = (const int*)d_in[1];
    const float* W1 = (const float*)d_in[2];
    const float* b1 = (const float*)d_in[3];
    const float* W2 = (const float*)d_in[4];
    const float* b2 = (const float*)d_in[5];
    const int n = in_sizes[0] / 64;   // 50000 (packed paths require n <= 65535)
    const int e = in_sizes[1] / 2;    // 1600000
    const int* src = ei;              // edge_index[0]
    const int* dst = ei + e;          // edge_index[1]

    char* ws = (char*)d_ws;
    size_t off = 0;
    auto alloc = [&](size_t bytes) -> void* {
        void* p = ws + off;
        off = (off + bytes + 255) & ~(size_t)255;
        return p;
    };
    unsigned* deg      = (unsigned*)alloc((size_t)n * 4);
    unsigned* rpf      = (unsigned*)alloc((size_t)(n + 1) * 4);
    float*    dinv     = (float*)alloc((size_t)n * 4);
    unsigned* partials = (unsigned*)alloc(1024 * 4);
    unsigned* cursor   = (unsigned*)alloc(128 * 4);
    unsigned* csr      = (unsigned*)alloc((size_t)e * 4);            // 6.4 MB node-major
    // ebuf dead after sortfill; xwh (fp16, 6.4 MB) overlays it.
    size_t ov = (size_t)e * 4 > (size_t)n * 64 * 2 ? (size_t)e * 4 : (size_t)n * 64 * 2;
    char*     overlay  = (char*)alloc(ov);
    unsigned* ebuf     = (unsigned*)overlay;
    __half*   xwh      = (__half*)overlay;
    float*    agg      = (float*)alloc((size_t)n * 64 * 4);          // 12.8 MB
    float*    outf     = (float*)d_out;

    const int nbS = (n + 1023) / 1024;         // 49 scan blocks
    const int B   = (n + 511) / 512;           // 98 buckets
    const int nbP1 = (e + P1_EDGES - 1) / P1_EDGES;  // 391

    // CSR build (shared by both layers)
    hipMemsetAsync(deg, 0, (size_t)n * 4, stream);
    degree_kernel<<<(e + 255) / 256, 256, 0, stream>>>(dst, deg, e);
    scan_local<<<nbS, 1024, 0, stream>>>(deg, rpf, partials, dinv, n);
    scan_partials<<<1, 1024, 0, stream>>>(partials, nbS);
    scan_add_kernel<<<(n + 1 + 255) / 256, 256, 0, stream>>>(rpf, partials, cursor, n, e);
    bucket_kernel<<<nbP1, 1024, 0, stream>>>(src, dst, cursor, ebuf, e, B);
    sortfill_kernel<<<B, 1024, 0, stream>>>(ebuf, rpf, dinv, csr, n);

    const int gblocks = (n + 15) / 16;

    // layer 1: xwh = fp16(x @ W1) ; agg = A_hat-gather(xwh)   (xwh overwrites dead ebuf)
    gemm64_kernel<<<gblocks, 256, 0, stream>>>((const float4*)x, W1, nullptr, 0, xwh, n);
    gather_kernel<<<gblocks, 256, 0, stream>>>(xwh, csr, rpf, dinv, nullptr, (float4*)agg, n);

    // layer 2: xwh = fp16(relu(agg + b1) @ W2) ; out = A_hat-gather(xwh) + b2
    gemm64_kernel<<<gblocks, 256, 0, stream>>>((const float4*)agg, W2, b1, 1, xwh, n);
    gather_kernel<<<gblocks, 256, 0, stream>>>(xwh, csr, rpf, dinv, b2, (float4*)outf, n);
}

// Round 9
// 232.816 us; speedup vs baseline: 1.6381x; 1.2814x over previous
//
#include <hip/hip_runtime.h>
#include <hip/hip_fp16.h>

// GCN 2-layer: out = A_hat @ relu(A_hat @ (X W1) + b1) W2 + b2
// A_hat = D^-1/2 (A+I) D^-1/2.
// R9: zero global-atomic degree. R8's degree_kernel cost 70 us / 50 MB WRITE
// (1.6M global atomicAdds = 1.6M memory-side RMW transactions). Replaced by:
//   bucket_count (LDS hist, 38k global atomics) -> scan_buckets (98 counts;
//   cursor identical to R8's rpf-derived one since rpf[512k] = sum of bucket
//   counts) -> bucket_scatter (unchanged) -> window_stats (per-bucket block
//   recounts its 512 nodes' degrees in LDS, local scan -> rpf, dinv).
// sortfill / gemm / gather unchanged from R8 (proven).

#define P1_EDGES 4096

// ---- bucket counting: LDS hist -> 98 global atomics per block ----
__global__ void bucket_count_kernel(const int* __restrict__ dst, unsigned* __restrict__ bcount,
                                    int e, int B) {
    __shared__ unsigned hist[128];
    for (int i = threadIdx.x; i < B; i += 1024) hist[i] = 0;
    __syncthreads();
    int e0 = blockIdx.x * P1_EDGES;
#pragma unroll
    for (int k = 0; k < 4; ++k) {
        int t = e0 + k * 1024 + threadIdx.x;
        if (t < e) atomicAdd(&hist[(unsigned)dst[t] >> 9], 1u);
    }
    __syncthreads();
    for (int i = threadIdx.x; i < B; i += 1024)
        if (hist[i]) atomicAdd(&bcount[i], hist[i]);
}

// ---- scan 98 bucket counts -> bstart (fixed) + cursor (mutable) ----
__global__ void scan_buckets(const unsigned* __restrict__ bcount, unsigned* __restrict__ bstart,
                             unsigned* __restrict__ cursor, unsigned* __restrict__ rpf,
                             int B, int n, int e) {
    __shared__ unsigned sh[128];
    unsigned v = (threadIdx.x < (unsigned)B) ? bcount[threadIdx.x] : 0u;
    sh[threadIdx.x] = v;
    __syncthreads();
    for (int off = 1; off < 128; off <<= 1) {
        unsigned t = (threadIdx.x >= (unsigned)off) ? sh[threadIdx.x - off] : 0u;
        __syncthreads();
        sh[threadIdx.x] += t;
        __syncthreads();
    }
    if (threadIdx.x < (unsigned)B) {
        unsigned s = sh[threadIdx.x] - v;  // exclusive
        bstart[threadIdx.x] = s;
        cursor[threadIdx.x] = s;
    }
    if (threadIdx.x == 0) { bstart[B] = (unsigned)e; rpf[n] = (unsigned)e; }
}

// ---- scatter edges by dst>>9 into ebuf bucket regions. ebuf = dst<<16|src ----
__global__ void bucket_kernel(const int* __restrict__ src, const int* __restrict__ dst,
                              unsigned* __restrict__ cursor, unsigned* __restrict__ ebuf,
                              int e, int B) {
    __shared__ unsigned hist[128];
    __shared__ unsigned base[128];
    for (int i = threadIdx.x; i < B; i += 1024) hist[i] = 0;
    __syncthreads();
    int e0 = blockIdx.x * P1_EDGES;
    unsigned bk[4], rk[4], pk[4];
    int cnt = 0;
#pragma unroll
    for (int k = 0; k < 4; ++k) {
        int t = e0 + k * 1024 + threadIdx.x;  // strided: coalesced reads
        if (t < e) {
            unsigned s = (unsigned)src[t], d = (unsigned)dst[t];
            unsigned b = d >> 9;
            bk[cnt] = b;
            rk[cnt] = atomicAdd(&hist[b], 1u);   // rank within (block,bucket)
            pk[cnt] = (d << 16) | s;             // n < 2^16: both fit
            cnt++;
        }
    }
    __syncthreads();
    for (int i = threadIdx.x; i < B; i += 1024)
        base[i] = hist[i] ? atomicAdd(&cursor[i], hist[i]) : 0u;
    __syncthreads();
    for (int k = 0; k < cnt; ++k)
        ebuf[base[bk[k]] + rk[k]] = pk[k];
}

// ---- per-bucket degree/rpf/dinv from ebuf: LDS atomics + local 512-scan ----
__global__ void window_stats_kernel(const unsigned* __restrict__ ebuf,
                                    const unsigned* __restrict__ bstart,
                                    unsigned* __restrict__ rpf, float* __restrict__ dinv, int n) {
    __shared__ unsigned pos[512];
    __shared__ unsigned sh[512];
    int b = blockIdx.x;
    int w0 = b << 9;
    int wlen = min(w0 + 512, n) - w0;
    if (threadIdx.x < 512) pos[threadIdx.x] = 0;
    __syncthreads();
    unsigned start = bstart[b], end = bstart[b + 1];
    for (unsigned j = start + threadIdx.x; j < end; j += 1024)
        atomicAdd(&pos[(ebuf[j] >> 16) - w0], 1u);
    __syncthreads();
    unsigned v = 0;
    if (threadIdx.x < 512) { v = pos[threadIdx.x]; sh[threadIdx.x] = v; }
    __syncthreads();
    for (int off = 1; off < 512; off <<= 1) {
        unsigned t = 0;
        if (threadIdx.x < 512 && threadIdx.x >= (unsigned)off) t = sh[threadIdx.x - off];
        __syncthreads();
        if (threadIdx.x < 512) sh[threadIdx.x] += t;
        __syncthreads();
    }
    if ((int)threadIdx.x < wlen) {
        rpf[w0 + threadIdx.x] = start + sh[threadIdx.x] - v;   // bucket base + excl
        dinv[w0 + threadIdx.x] = rsqrtf((float)v + 1.0f);      // +1 self-loop
    }
}

// ---- per-bucket fill: LDS pos counters; csr writes in one 64 KB window ----
__global__ void sortfill_kernel(const unsigned* __restrict__ ebuf, const unsigned* __restrict__ rpf,
                                const float* __restrict__ dinv, unsigned* __restrict__ csr, int n) {
    __shared__ unsigned pos[512];
    __shared__ unsigned rpl[512];
    __shared__ float dl[512];
    int w0 = blockIdx.x << 9;
    int w1 = min(w0 + 512, n);
    int wlen = w1 - w0;
    for (int i = threadIdx.x; i < 512; i += 1024) {
        pos[i] = 0;
        if (i < wlen) {
            rpl[i] = rpf[w0 + i];
            dl[i] = dinv[w0 + i];
        }
    }
    __syncthreads();
    unsigned start = rpf[w0], end = rpf[w1];
    for (unsigned j = start + threadIdx.x; j < end; j += 1024) {
        unsigned p = ebuf[j];
        unsigned d = p >> 16;
        unsigned s = p & 0xffffu;
        float norm = dinv[s] * dl[d - w0];                              // in (0, 1]
        unsigned nb = (__float_as_uint(norm) + 0x8000u) & 0xffff0000u;  // rn bf16
        unsigned r = atomicAdd(&pos[d - w0], 1u);
        csr[rpl[d - w0] + r] = nb | s;
    }
}

// ---- Yh[n,64] (fp16) = f(X[n,64]) @ W[64,64]; 16 lanes/row, 4 rows/wave ----
__global__ void gemm64_kernel(const float4* __restrict__ X4, const float* __restrict__ W,
                              const float* __restrict__ bias, int do_relu,
                              __half* __restrict__ Yh, int n) {
    __shared__ float4 Ws[64][16];  // Ws[k][l] = W[k][4l..4l+3]
    for (int i = threadIdx.x; i < 64 * 16; i += blockDim.x)
        Ws[i >> 4][i & 15] = ((const float4*)W)[i];
    __syncthreads();
    int lane = threadIdx.x & 63;
    int l = lane & 15;
    int gbase = lane & 48;
    int wid = blockIdx.x * (blockDim.x >> 6) + (threadIdx.x >> 6);
    int row = wid * 4 + (lane >> 4);
    if (row >= n) return;
    float4 xv = X4[(size_t)row * 16 + l];
    if (bias) {
        float4 b = ((const float4*)bias)[l];
        xv.x += b.x; xv.y += b.y; xv.z += b.z; xv.w += b.w;
    }
    if (do_relu) {
        xv.x = fmaxf(xv.x, 0.f); xv.y = fmaxf(xv.y, 0.f);
        xv.z = fmaxf(xv.z, 0.f); xv.w = fmaxf(xv.w, 0.f);
    }
    float4 acc = make_float4(0.f, 0.f, 0.f, 0.f);
#pragma unroll
    for (int k = 0; k < 64; ++k) {
        float comp = (k & 3) == 0 ? xv.x : (k & 3) == 1 ? xv.y : (k & 3) == 2 ? xv.z : xv.w;
        float a = __shfl(comp, gbase + (k >> 2));
        float4 w = Ws[k][l];
        acc.x = fmaf(a, w.x, acc.x); acc.y = fmaf(a, w.y, acc.y);
        acc.z = fmaf(a, w.z, acc.z); acc.w = fmaf(a, w.w, acc.w);
    }
    __half2 h0 = __floats2half2_rn(acc.x, acc.y);
    __half2 h1 = __floats2half2_rn(acc.z, acc.w);
    uint2 o;
    o.x = *(const unsigned*)&h0;
    o.y = *(const unsigned*)&h1;
    *(uint2*)(Yh + (size_t)row * 64 + 4 * l) = o;
}

// ---- gather: 16-lane group per dst node; lane l owns cols 4l..4l+3 (fp16 xw) ----
__global__ void gather_kernel(const __half* __restrict__ xwh, const unsigned* __restrict__ csr,
                              const unsigned* __restrict__ row_ptr, const float* __restrict__ dinv,
                              const float* __restrict__ bias, float4* __restrict__ out4, int n) {
    int lane = threadIdx.x & 63;
    int l = lane & 15;
    int gbase = lane & 48;
    int wid = blockIdx.x * (blockDim.x >> 6) + (threadIdx.x >> 6);
    int row = wid * 4 + (lane >> 4);
    if (row >= n) return;  // 16-lane group exits together; shfl stays in-group
    unsigned start = row_ptr[row], end = row_ptr[row + 1];
    float di = dinv[row];
    float s2 = di * di;
    float4 acc;
    {   // self-loop term
        uint2 hv = *(const uint2*)(xwh + (size_t)row * 64 + 4 * l);
        float2 f0 = __half22float2(*(const __half2*)&hv.x);
        float2 f1 = __half22float2(*(const __half2*)&hv.y);
        acc = make_float4(f0.x * s2, f0.y * s2, f1.x * s2, f1.y * s2);
    }
    if (bias) {
        float4 b = ((const float4*)bias)[l];
        acc.x += b.x; acc.y += b.y; acc.z += b.z; acc.w += b.w;
    }
    for (unsigned base = start; base < end; base += 16) {
        int j = (int)(base + (unsigned)l);
        unsigned ed = (j < (int)end) ? __builtin_nontemporal_load(&csr[j]) : 0u;
        int cnt = (int)min(16u, end - base);
#pragma unroll
        for (int t = 0; t < 16; ++t) {
            unsigned p = __shfl(ed, gbase + t);
            int st = (int)(p & 0xffffu);                   // src (< 2^16: safe)
            float nrm = __uint_as_float(p & 0xffff0000u);  // bf16 -> f32 = mask
            nrm = (t < cnt) ? nrm : 0.0f;                  // predicate tail
            uint2 hv = *(const uint2*)(xwh + (size_t)st * 64 + 4 * l);
            float2 f0 = __half22float2(*(const __half2*)&hv.x);
            float2 f1 = __half22float2(*(const __half2*)&hv.y);
            acc.x = fmaf(nrm, f0.x, acc.x); acc.y = fmaf(nrm, f0.y, acc.y);
            acc.z = fmaf(nrm, f1.x, acc.z); acc.w = fmaf(nrm, f1.y, acc.w);
        }
    }
    out4[(size_t)row * 16 + l] = acc;
}

extern "C" void kernel_launch(void* const* d_in, const int* in_sizes, int n_in,
                              void* d_out, int out_size, void* d_ws, size_t ws_size,
                              hipStream_t stream) {
    const float* x  = (const float*)d_in[0];
    const int*   ei = (const int*)d_in[1];
    const float* W1 = (const float*)d_in[2];
    const float* b1 = (const float*)d_in[3];
    const float* W2 = (const float*)d_in[4];
    const float* b2 = (const float*)d_in[5];
    const int n = in_sizes[0] / 64;   // 50000 (packed paths require n <= 65535)
    const int e = in_sizes[1] / 2;    // 1600000
    const int* src = ei;              // edge_index[0]
    const int* dst = ei + e;          // edge_index[1]

    char* ws = (char*)d_ws;
    size_t off = 0;
    auto alloc = [&](size_t bytes) -> void* {
        void* p = ws + off;
        off = (off + bytes + 255) & ~(size_t)255;
        return p;
    };
    unsigned* rpf      = (unsigned*)alloc((size_t)(n + 1) * 4);
    float*    dinv     = (float*)alloc((size_t)n * 4);
    unsigned* bcount   = (unsigned*)alloc(128 * 4);
    unsigned* bstart   = (unsigned*)alloc(129 * 4);
    unsigned* cursor   = (unsigned*)alloc(128 * 4);
    unsigned* csr      = (unsigned*)alloc((size_t)e * 4);            // 6.4 MB node-major
    // ebuf dead after sortfill; xwh (fp16, 6.4 MB) overlays it.
    size_t ov = (size_t)e * 4 > (size_t)n * 64 * 2 ? (size_t)e * 4 : (size_t)n * 64 * 2;
    char*     overlay  = (char*)alloc(ov);
    unsigned* ebuf     = (unsigned*)overlay;
    __half*   xwh      = (__half*)overlay;
    float*    agg      = (float*)alloc((size_t)n * 64 * 4);          // 12.8 MB
    float*    outf     = (float*)d_out;

    const int B    = (n + 511) / 512;                 // 98 buckets
    const int nbP1 = (e + P1_EDGES - 1) / P1_EDGES;   // 391

    // CSR build (shared by both layers) — no global-atomic degree pass
    hipMemsetAsync(bcount, 0, 128 * 4, stream);
    bucket_count_kernel<<<nbP1, 1024, 0, stream>>>(dst, bcount, e, B);
    scan_buckets<<<1, 128, 0, stream>>>(bcount, bstart, cursor, rpf, B, n, e);
    bucket_kernel<<<nbP1, 1024, 0, stream>>>(src, dst, cursor, ebuf, e, B);
    window_stats_kernel<<<B, 1024, 0, stream>>>(ebuf, bstart, rpf, dinv, n);
    sortfill_kernel<<<B, 1024, 0, stream>>>(ebuf, rpf, dinv, csr, n);

    const int gblocks = (n + 15) / 16;

    // layer 1: xwh = fp16(x @ W1) ; agg = A_hat-gather(xwh)   (xwh overwrites dead ebuf)
    gemm64_kernel<<<gblocks, 256, 0, stream>>>((const float4*)x, W1, nullptr, 0, xwh, n);
    gather_kernel<<<gblocks, 256, 0, stream>>>(xwh, csr, rpf, dinv, nullptr, (float4*)agg, n);

    // layer 2: xwh = fp16(relu(agg + b1) @ W2) ; out = A_hat-gather(xwh) + b2
    gemm64_kernel<<<gblocks, 256, 0, stream>>>((const float4*)agg, W2, b1, 1, xwh, n);
    gather_kernel<<<gblocks, 256, 0, stream>>>(xwh, csr, rpf, dinv, b2, (float4*)outf, n);
}